// Round 14
// baseline (232.071 us; speedup 1.0000x reference)
//
#include <hip/hip_runtime.h>

#define VOCAB 53
#define EDIM  16
#define H     32
#define SEQ   512
#define BATCH 4096
#define LOG2E 1.4426950408889634f
#define HS    72    // h-buffer per-col stride in f16 (even 8-quad bank spread)
#define RSC   2048.0f      // residual scale (2^11): lo parts stay f16-normal
#define RSCI  (1.0f/2048.0f)

typedef _Float16 f16x8 __attribute__((ext_vector_type(8)));
typedef float f32x4 __attribute__((ext_vector_type(4)));

__device__ __forceinline__ float exp2_hw(float x) {
    float r; asm("v_exp_f32 %0, %1" : "=v"(r) : "v"(x)); return r;
}
// rcp(1 + 2^xs): sigmoid when xs = -log2e * z (scales pre-folded into tables)
__device__ __forceinline__ float sig_exp2(float xs) {
    return __builtin_amdgcn_rcpf(1.0f + exp2_hw(xs));
}

// permuted row rp = 16*m + 4*s + g  <->  original W row g*32 + (4m+s)
// (mfma chunk m gives lane (q,c) the 4 gates i,f,g,o of unit 4m+q in D[0..3])
__device__ __forceinline__ void decode_row(int rp, int& orig, float& scale) {
    int m = rp >> 4, rem = rp & 15, s = rem >> 2, g = rem & 3;
    orig = g * 32 + 4 * m + s;
    scale = (g == 2) ? (-2.0f * LOG2E) : (-LOG2E);   // g doubled: tanh(g)=2*sig(2g)-1
}

// ---- kernel 1: vocab -> permuted scaled preactivation table in GLOBAL d_ws.
// 27 KB, L1/L2-resident for the main kernel: per-step xg reads ride the
// otherwise-idle VMEM pipe instead of the saturated DS pipe.
__global__ void build_xg(const float* __restrict__ emb,
                         const float* __restrict__ W_ih,
                         const float* __restrict__ b_ih,
                         const float* __restrict__ b_hh,
                         float* __restrict__ xg_g) {
    int idx = blockIdx.x * 256 + threadIdx.x;
    if (idx >= VOCAB * 128) return;
    int v = idx >> 7, rp = idx & 127;
    int orig; float scale; decode_row(rp, orig, scale);
    float acc = b_ih[orig] + b_hh[orig];
    const float* ev = emb + v * EDIM;
    const float* wr = W_ih + orig * EDIM;
#pragma unroll
    for (int e = 0; e < EDIM; ++e) acc += ev[e] * wr[e];
    xg_g[v * 128 + rp] = scale * acc;
}

// ---- kernel 2: 256 blocks x 512 threads (8 waves, R8 geometry). Each block
// owns 16 batch elements; each wave one 16-row MFMA chunk. h exchanged via
// double-buffered padded LDS planes (hi + x2048 residual). Per-step barrier is
// RELAXED: s_waitcnt lgkmcnt(0) + raw s_barrier — orders the LDS h-exchange
// but leaves VMEM prefetches (xg 1 step ahead, tokens 2 ahead) in flight
// across the barrier (avoids __syncthreads' vmcnt(0) drain, the R11 killer).
// 3 independent MFMAs reconstruct near-f32 precision; c scaled by -2log2e.
__global__ __launch_bounds__(512)
__attribute__((amdgpu_waves_per_eu(2, 2)))   // exactly our occupancy: no VGPR squeeze
void lstm_seq_classifier(const int* __restrict__ x,
                         const float* __restrict__ W_hh,
                         const float* __restrict__ W_fc,
                         const float* __restrict__ b_fc,
                         const float* __restrict__ xg_g,
                         float* __restrict__ out) {
    __shared__ _Float16 whi[128 * 32];                      // 8,192 B
    __shared__ _Float16 wlo[128 * 32];                      // 8,192 B (x2048 residual)
    __shared__ __align__(16) _Float16 hhi_buf[2][16][HS];   // 4,608 B
    __shared__ __align__(16) _Float16 hlo_buf[2][16][HS];   // 4,608 B
    __shared__ float red[16 * 33];                          // 2,112 B

    const int tid  = threadIdx.x;
    const int lane = tid & 63;
    const int w    = tid >> 6;      // wave index = mfma row-chunk m
    const int col  = lane & 15;     // batch column
    const int q    = lane >> 4;

    // ---- permuted scaled W_hh as f16 hi + scaled f16 residual ----
    for (int idx = tid; idx < 128 * 32; idx += 512) {
        int rp = idx >> 5, k = idx & 31;
        int orig; float scale; decode_row(rp, orig, scale);
        float wv = scale * W_hh[orig * H + k];
        _Float16 hi = (_Float16)wv;
        whi[idx] = hi;
        wlo[idx] = (_Float16)((wv - (float)hi) * RSC);
    }
    for (int idx = tid; idx < 2 * 16 * HS; idx += 512) {
        (&hhi_buf[0][0][0])[idx] = (_Float16)0.f;
        (&hlo_buf[0][0][0])[idx] = (_Float16)0.f;
    }
    __syncthreads();   // full sync once (weights staged)

    // A fragments: chunk-row = col, k-slot j = unit 8q+j (identity k-order)
    const f16x8 Ahi = *reinterpret_cast<const f16x8*>(&whi[(16 * w + col) * 32 + 8 * q]);
    const f16x8 Alo = *reinterpret_cast<const f16x8*>(&wlo[(16 * w + col) * 32 + 8 * q]);

    const long xb = (long)(blockIdx.x * 16 + col) * SEQ;
    const int xoff = 16 * w + 4 * q;          // this lane's 4 rows in the table
    int vc = x[xb + 1];
    f32x4 xg_cur = *reinterpret_cast<const f32x4*>(&xg_g[x[xb] * 128 + xoff]);

    float ccs = 0.0f, h = 0.0f;   // ccs = -2log2e * c
    const f32x4 zeroC = {0.f, 0.f, 0.f, 0.f};

    for (int s = 0; s < SEQ; ++s) {
        int vn = x[xb + ((s + 2) & (SEQ - 1))];                      // prefetch s+2
        f32x4 xg_nxt = *reinterpret_cast<const f32x4*>(
            &xg_g[vc * 128 + xoff]);                                 // global, 1 step ahead
        const int rb = s & 1, nb = rb ^ 1;
        f16x8 Bhi = *reinterpret_cast<const f16x8*>(&hhi_buf[rb][col][8 * q]);
        f16x8 Blo = *reinterpret_cast<const f16x8*>(&hlo_buf[rb][col][8 * q]);

        // three INDEPENDENT MFMAs (1-deep chain), then combine
        f32x4 D   = __builtin_amdgcn_mfma_f32_16x16x32_f16(Ahi, Bhi, xg_cur, 0, 0, 0);
        f32x4 Dra = __builtin_amdgcn_mfma_f32_16x16x32_f16(Alo, Bhi, zeroC, 0, 0, 0);
        f32x4 Drb = __builtin_amdgcn_mfma_f32_16x16x32_f16(Ahi, Blo, zeroC, 0, 0, 0);

        float zi = __builtin_fmaf(RSCI, Dra[0] + Drb[0], D[0]);
        float zf = __builtin_fmaf(RSCI, Dra[1] + Drb[1], D[1]);
        float zg = __builtin_fmaf(RSCI, Dra[2] + Drb[2], D[2]);
        float zo = __builtin_fmaf(RSCI, Dra[3] + Drb[3], D[3]);

        float si = sig_exp2(zi);                         // sigma(i)
        float sf = sig_exp2(zf);                         // sigma(f)
        float ug = sig_exp2(zg);                         // sigma(2g)
        float so = sig_exp2(zo);                         // sigma(o)
        float t1 = __builtin_fmaf(-4.0f * LOG2E, ug, 2.0f * LOG2E);  // -2l2e*tanh(g)
        ccs = __builtin_fmaf(sf, ccs, si * t1);          // scaled cell
        float tc = __builtin_fmaf(2.0f, sig_exp2(ccs), -1.0f);       // tanh(c)
        h = so * tc;

        _Float16 hf = (_Float16)h;
        hhi_buf[nb][col][4 * w + q] = hf;
        hlo_buf[nb][col][4 * w + q] = (_Float16)((h - (float)hf) * RSC);

        // relaxed barrier: order LDS only; leave VMEM prefetches in flight
        asm volatile("s_waitcnt lgkmcnt(0)" ::: "memory");
        __builtin_amdgcn_s_barrier();

        xg_cur = xg_nxt;
        vc = vn;
    }

    // ---- final FC (1 unit) + sigmoid: cross-wave reduce over the 32 units ----
    red[col * 33 + 4 * w + q] = h * W_fc[4 * w + q];
    __syncthreads();
    if (w == 0) {
        const float* rr = &red[col * 33];
        float p = 0.f;
#pragma unroll
        for (int u = 0; u < 8; ++u) p += rr[8 * q + u];
        p += __shfl_xor(p, 16);
        p += __shfl_xor(p, 32);
        if (lane < 16) {
            out[blockIdx.x * 16 + col] = sig_exp2(-LOG2E * (p + b_fc[0]));
        }
    }
}

extern "C" void kernel_launch(void* const* d_in, const int* in_sizes, int n_in,
                              void* d_out, int out_size, void* d_ws, size_t ws_size,
                              hipStream_t stream) {
    const int*   x    = (const int*)d_in[0];
    const float* emb  = (const float*)d_in[1];
    const float* W_ih = (const float*)d_in[2];
    const float* W_hh = (const float*)d_in[3];
    const float* b_ih = (const float*)d_in[4];
    const float* b_hh = (const float*)d_in[5];
    const float* W_fc = (const float*)d_in[6];
    const float* b_fc = (const float*)d_in[7];
    float* out  = (float*)d_out;
    float* xg_g = (float*)d_ws;     // 53*128*4 = 27,136 B of scratch

    dim3 gb((VOCAB * 128 + 255) / 256);
    build_xg<<<gb, 256, 0, stream>>>(emb, W_ih, b_ih, b_hh, xg_g);

    dim3 grid(BATCH / 16);   // 256 blocks: one 16-elem group per block (1/CU)
    dim3 block(512);         // 8 waves, one mfma row-chunk each
    lstm_seq_classifier<<<grid, block, 0, stream>>>(x, W_hh, W_fc, b_fc,
                                                    xg_g, out);
}

// Round 15
// 170.587 us; speedup vs baseline: 1.3604x; 1.3604x over previous
//
#include <hip/hip_runtime.h>

#define VOCAB 53
#define EDIM  16
#define H     32
#define SEQ   512
#define BATCH 4096
#define LOG2E 1.4426950408889634f
#define XRS   132   // xg row stride in f32 words (%4==0 for b128 alignment)
#define HS    72    // h-buffer per-col stride in f16
#define RSC   2048.0f      // residual scale (2^11): lo parts stay f16-normal
#define RSCI  (1.0f/2048.0f)

typedef _Float16 f16x8 __attribute__((ext_vector_type(8)));
typedef float f32x4 __attribute__((ext_vector_type(4)));

__device__ __forceinline__ float exp2_hw(float x) {
    float r; asm("v_exp_f32 %0, %1" : "=v"(r) : "v"(x)); return r;
}
// rcp(1 + 2^xs): sigmoid when xs = -log2e * z (scales pre-folded into tables)
__device__ __forceinline__ float sig_exp2(float xs) {
    return __builtin_amdgcn_rcpf(1.0f + exp2_hw(xs));
}

// permuted row rp = 16*m + 4*s + g  <->  original W row g*32 + (4m+s)
// (mfma chunk m gives lane (q,c) the 4 gates i,f,g,o of unit 4m+q in D[0..3])
__device__ __forceinline__ void decode_row(int rp, int& orig, float& scale) {
    int m = rp >> 4, rem = rp & 15, s = rem >> 2, g = rem & 3;
    orig = g * 32 + 4 * m + s;
    scale = (g == 2) ? (-2.0f * LOG2E) : (-LOG2E);   // g doubled: tanh(g)=2*sig(2g)-1
}

// 256 blocks x 512 threads (8 waves). Each block owns 16 batch elements; each
// wave one 16-row MFMA chunk. h exchanged via double-buffered padded LDS
// planes (hi + x2048 residual); xg table in LDS (beats global by ~70us: no
// vmcnt stall in-chain). 2x-unrolled loop pins buffer parities statically;
// relaxed barrier (lgkmcnt-only) keeps token prefetch in flight; setprio(1)
// covers the read->MFMA->sigma critical section.
__global__ __launch_bounds__(512)
__attribute__((amdgpu_waves_per_eu(2, 2)))
void lstm_seq_classifier(const int* __restrict__ x,
                         const float* __restrict__ emb,
                         const float* __restrict__ W_ih,
                         const float* __restrict__ W_hh,
                         const float* __restrict__ b_ih,
                         const float* __restrict__ b_hh,
                         const float* __restrict__ W_fc,
                         const float* __restrict__ b_fc,
                         float* __restrict__ out) {
    __shared__ float xg_perm[VOCAB * XRS];                  // 27,984 B (f32 exact)
    __shared__ _Float16 whi[128 * 32];                      // 8,192 B
    __shared__ _Float16 wlo[128 * 32];                      // 8,192 B (x2048 residual)
    __shared__ __align__(16) _Float16 hhi_buf[2][16][HS];   // 4,608 B
    __shared__ __align__(16) _Float16 hlo_buf[2][16][HS];   // 4,608 B
    __shared__ float red[16 * 33];                          // 2,112 B

    const int tid  = threadIdx.x;
    const int lane = tid & 63;
    const int w    = tid >> 6;      // wave index = mfma row-chunk m
    const int col  = lane & 15;     // batch column
    const int q    = lane >> 4;

    // ---- vocab -> permuted, scaled gate-preactivation table (f32 exact) ----
    for (int idx = tid; idx < VOCAB * 128; idx += 512) {
        int v = idx >> 7, rp = idx & 127;
        int orig; float scale; decode_row(rp, orig, scale);
        float acc = b_ih[orig] + b_hh[orig];
        const float* ev = emb + v * EDIM;
        const float* wr = W_ih + orig * EDIM;
#pragma unroll
        for (int e = 0; e < EDIM; ++e) acc += ev[e] * wr[e];
        xg_perm[v * XRS + rp] = scale * acc;
    }
    // ---- permuted scaled W_hh as f16 hi + scaled f16 residual ----
    for (int idx = tid; idx < 128 * 32; idx += 512) {
        int rp = idx >> 5, k = idx & 31;
        int orig; float scale; decode_row(rp, orig, scale);
        float wv = scale * W_hh[orig * H + k];
        _Float16 hi = (_Float16)wv;
        whi[idx] = hi;
        wlo[idx] = (_Float16)((wv - (float)hi) * RSC);
    }
    for (int idx = tid; idx < 2 * 16 * HS; idx += 512) {
        (&hhi_buf[0][0][0])[idx] = (_Float16)0.f;
        (&hlo_buf[0][0][0])[idx] = (_Float16)0.f;
    }
    __syncthreads();

    // A fragments: chunk-row = col, k-slot j = unit 8q+j (identity k-order)
    const f16x8 Ahi = *reinterpret_cast<const f16x8*>(&whi[(16 * w + col) * 32 + 8 * q]);
    const f16x8 Alo = *reinterpret_cast<const f16x8*>(&wlo[(16 * w + col) * 32 + 8 * q]);

    const long xb = (long)(blockIdx.x * 16 + col) * SEQ;
    const int xoff = 16 * w + 4 * q;
    int vc = x[xb + 1];
    f32x4 xg_cur = *reinterpret_cast<const f32x4*>(&xg_perm[x[xb] * XRS + xoff]);

    float ccs = 0.0f, h = 0.0f;   // ccs = -2log2e * c
    const f32x4 zeroC = {0.f, 0.f, 0.f, 0.f};

    // static per-parity addresses
    const _Float16* rd_hi0 = &hhi_buf[0][col][8 * q];
    const _Float16* rd_lo0 = &hlo_buf[0][col][8 * q];
    const _Float16* rd_hi1 = &hhi_buf[1][col][8 * q];
    const _Float16* rd_lo1 = &hlo_buf[1][col][8 * q];
    _Float16* wr_hi0 = &hhi_buf[1][col][4 * w + q];   // write plane when reading 0
    _Float16* wr_lo0 = &hlo_buf[1][col][4 * w + q];
    _Float16* wr_hi1 = &hhi_buf[0][col][4 * w + q];
    _Float16* wr_lo1 = &hlo_buf[0][col][4 * w + q];

#define STEP(S, RDHI, RDLO, WRHI, WRLO)                                       \
    {                                                                         \
        __builtin_amdgcn_s_setprio(1);                                        \
        f16x8 Bhi = *reinterpret_cast<const f16x8*>(RDHI);                    \
        f16x8 Blo = *reinterpret_cast<const f16x8*>(RDLO);                    \
        f32x4 xg_nxt = *reinterpret_cast<const f32x4*>(                       \
            &xg_perm[vc * XRS + xoff]);                                       \
        int vn = x[xb + (((S) + 2) & (SEQ - 1))];                             \
        f32x4 D   = __builtin_amdgcn_mfma_f32_16x16x32_f16(Ahi, Bhi, xg_cur, 0, 0, 0); \
        f32x4 Dra = __builtin_amdgcn_mfma_f32_16x16x32_f16(Alo, Bhi, zeroC, 0, 0, 0);  \
        f32x4 Drb = __builtin_amdgcn_mfma_f32_16x16x32_f16(Ahi, Blo, zeroC, 0, 0, 0);  \
        float zi = __builtin_fmaf(RSCI, Dra[0] + Drb[0], D[0]);               \
        float zf = __builtin_fmaf(RSCI, Dra[1] + Drb[1], D[1]);               \
        float zg = __builtin_fmaf(RSCI, Dra[2] + Drb[2], D[2]);               \
        float zo = __builtin_fmaf(RSCI, Dra[3] + Drb[3], D[3]);               \
        float si = sig_exp2(zi);                                              \
        float sf = sig_exp2(zf);                                              \
        float ug = sig_exp2(zg);                                              \
        float so = sig_exp2(zo);                                              \
        float t1 = __builtin_fmaf(-4.0f * LOG2E, ug, 2.0f * LOG2E);           \
        ccs = __builtin_fmaf(sf, ccs, si * t1);                               \
        float so2 = so + so;                                                  \
        float sc = sig_exp2(ccs);                                             \
        h = __builtin_fmaf(so2, sc, -so);                                     \
        __builtin_amdgcn_s_setprio(0);                                        \
        _Float16 hf = (_Float16)h;                                            \
        *(WRHI) = hf;                                                         \
        *(WRLO) = (_Float16)((h - (float)hf) * RSC);                          \
        asm volatile("s_waitcnt lgkmcnt(0)" ::: "memory");                    \
        __builtin_amdgcn_s_barrier();                                         \
        xg_cur = xg_nxt;                                                      \
        vc = vn;                                                              \
    }

    for (int s = 0; s < SEQ; s += 2) {
        STEP(s,     rd_hi0, rd_lo0, wr_hi0, wr_lo0)   // even: read buf0, write buf1
        STEP(s + 1, rd_hi1, rd_lo1, wr_hi1, wr_lo1)   // odd : read buf1, write buf0
    }
#undef STEP

    // ---- final FC (1 unit) + sigmoid: cross-wave reduce over the 32 units ----
    red[col * 33 + 4 * w + q] = h * W_fc[4 * w + q];
    __syncthreads();
    if (w == 0) {
        const float* rr = &red[col * 33];
        float p = 0.f;
#pragma unroll
        for (int u = 0; u < 8; ++u) p += rr[8 * q + u];
        p += __shfl_xor(p, 16);
        p += __shfl_xor(p, 32);
        if (lane < 16) {
            out[blockIdx.x * 16 + col] = sig_exp2(-LOG2E * (p + b_fc[0]));
        }
    }
}

extern "C" void kernel_launch(void* const* d_in, const int* in_sizes, int n_in,
                              void* d_out, int out_size, void* d_ws, size_t ws_size,
                              hipStream_t stream) {
    const int*   x    = (const int*)d_in[0];
    const float* emb  = (const float*)d_in[1];
    const float* W_ih = (const float*)d_in[2];
    const float* W_hh = (const float*)d_in[3];
    const float* b_ih = (const float*)d_in[4];
    const float* b_hh = (const float*)d_in[5];
    const float* W_fc = (const float*)d_in[6];
    const float* b_fc = (const float*)d_in[7];
    float* out = (float*)d_out;

    dim3 grid(BATCH / 16);   // 256 blocks: one 16-elem group per block (1/CU)
    dim3 block(512);         // 8 waves, one mfma row-chunk each
    lstm_seq_classifier<<<grid, block, 0, stream>>>(x, emb, W_ih, W_hh,
                                                    b_ih, b_hh, W_fc, b_fc, out);
}

// Round 16
// 163.510 us; speedup vs baseline: 1.4193x; 1.0433x over previous
//
#include <hip/hip_runtime.h>

#define VOCAB 53
#define EDIM  16
#define H     32
#define SEQ   512
#define BATCH 4096
#define LOG2E 1.4426950408889634f
#define XRS   132   // xg row stride in f32 words (%4==0 for b128 alignment)
#define HS    72    // h-buffer per-col stride in f16
#define RSC   2048.0f      // residual scale (2^11): lo parts stay f16-normal
#define RSCI  (1.0f/2048.0f)

typedef _Float16 f16x8 __attribute__((ext_vector_type(8)));
typedef float f32x4 __attribute__((ext_vector_type(4)));

__device__ __forceinline__ float exp2_hw(float x) {
    float r; asm("v_exp_f32 %0, %1" : "=v"(r) : "v"(x)); return r;
}
// rcp(1 + 2^xs): sigmoid when xs = -log2e * z (scales pre-folded into tables)
__device__ __forceinline__ float sig_exp2(float xs) {
    return __builtin_amdgcn_rcpf(1.0f + exp2_hw(xs));
}

// permuted row rp = 16*m + 4*s + g  <->  original W row g*32 + (4m+s)
// (mfma chunk m gives lane (q,c) the 4 gates i,f,g,o of unit 4m+q in D[0..3])
__device__ __forceinline__ void decode_row(int rp, int& orig, float& scale) {
    int m = rp >> 4, rem = rp & 15, s = rem >> 2, g = rem & 3;
    orig = g * 32 + 4 * m + s;
    scale = (g == 2) ? (-2.0f * LOG2E) : (-LOG2E);   // g doubled: tanh(g)=2*sig(2g)-1
}

// k-slot -> unit permutation: slot s holds h of unit pi(s); chosen so the
// h-WRITE of unit 4w+q goes to slot 2q+(w&1)+8(w>>1), spreading the 64 lanes
// of each ds_write_b16 across all 32 banks exactly 2-way (free; was 4-way).
__device__ __forceinline__ int pi_slot_unit(int s) {
    return 8 * (s >> 3) + 4 * (s & 1) + ((s >> 1) & 3);
}

// 256 blocks x 512 threads (8 waves) — R8 structure. Each block owns 16 batch
// elements; each wave one 16-row MFMA chunk. h exchanged via double-buffered
// padded LDS planes (hi + x2048 residual) with the bank-spreading k-slot
// permutation. Per-step barrier is lgkm-only (token prefetch stays in flight).
// xg_nxt/token prefetches issue AFTER the MFMAs (sched_barrier fence) to thin
// the post-barrier DS burst. 3 independent MFMAs give near-f32 precision;
// c kept scaled by -2log2e.
__global__ __launch_bounds__(512, 1)
void lstm_seq_classifier(const int* __restrict__ x,
                         const float* __restrict__ emb,
                         const float* __restrict__ W_ih,
                         const float* __restrict__ W_hh,
                         const float* __restrict__ b_ih,
                         const float* __restrict__ b_hh,
                         const float* __restrict__ W_fc,
                         const float* __restrict__ b_fc,
                         float* __restrict__ out) {
    __shared__ float xg_perm[VOCAB * XRS];                  // 27,984 B (f32 exact)
    __shared__ _Float16 whi[128 * 32];                      // 8,192 B
    __shared__ _Float16 wlo[128 * 32];                      // 8,192 B (x2048 residual)
    __shared__ __align__(16) _Float16 hhi_buf[2][16][HS];   // 4,608 B
    __shared__ __align__(16) _Float16 hlo_buf[2][16][HS];   // 4,608 B
    __shared__ float red[16 * 33];                          // 2,112 B

    const int tid  = threadIdx.x;
    const int lane = tid & 63;
    const int w    = tid >> 6;      // wave index = mfma row-chunk m
    const int col  = lane & 15;     // batch column
    const int q    = lane >> 4;

    // ---- vocab -> permuted, scaled gate-preactivation table (f32 exact) ----
    for (int idx = tid; idx < VOCAB * 128; idx += 512) {
        int v = idx >> 7, rp = idx & 127;
        int orig; float scale; decode_row(rp, orig, scale);
        float acc = b_ih[orig] + b_hh[orig];
        const float* ev = emb + v * EDIM;
        const float* wr = W_ih + orig * EDIM;
#pragma unroll
        for (int e = 0; e < EDIM; ++e) acc += ev[e] * wr[e];
        xg_perm[v * XRS + rp] = scale * acc;
    }
    // ---- permuted scaled W_hh as f16 hi + scaled f16 residual.
    //      k-slot k of row rp holds W[orig(rp)][pi(k)]  (B uses same pi) ----
    for (int idx = tid; idx < 128 * 32; idx += 512) {
        int rp = idx >> 5, k = idx & 31;
        int orig; float scale; decode_row(rp, orig, scale);
        int ku = pi_slot_unit(k);
        float wv = scale * W_hh[orig * H + ku];
        _Float16 hi = (_Float16)wv;
        whi[idx] = hi;
        wlo[idx] = (_Float16)((wv - (float)hi) * RSC);
    }
    for (int idx = tid; idx < 2 * 16 * HS; idx += 512) {
        (&hhi_buf[0][0][0])[idx] = (_Float16)0.f;
        (&hlo_buf[0][0][0])[idx] = (_Float16)0.f;
    }
    __syncthreads();

    // A fragments: chunk-row = col, k-slots 8q..8q+7
    const f16x8 Ahi = *reinterpret_cast<const f16x8*>(&whi[(16 * w + col) * 32 + 8 * q]);
    const f16x8 Alo = *reinterpret_cast<const f16x8*>(&wlo[(16 * w + col) * 32 + 8 * q]);

    const long xb = (long)(blockIdx.x * 16 + col) * SEQ;
    const int xoff = 16 * w + 4 * q;
    const int wslot = 2 * q + (w & 1) + 8 * (w >> 1);   // bank-spread write slot
    int vc = x[xb + 1];
    f32x4 xg_cur = *reinterpret_cast<const f32x4*>(&xg_perm[x[xb] * XRS + xoff]);

    float ccs = 0.0f, h = 0.0f;   // ccs = -2log2e * c
    const f32x4 zeroC = {0.f, 0.f, 0.f, 0.f};

    for (int s = 0; s < SEQ; ++s) {
        const int rb = s & 1, nb = rb ^ 1;
        f16x8 Bhi = *reinterpret_cast<const f16x8*>(&hhi_buf[rb][col][8 * q]);
        f16x8 Blo = *reinterpret_cast<const f16x8*>(&hlo_buf[rb][col][8 * q]);

        // three INDEPENDENT MFMAs (1-deep chain)
        f32x4 D   = __builtin_amdgcn_mfma_f32_16x16x32_f16(Ahi, Bhi, xg_cur, 0, 0, 0);
        f32x4 Dra = __builtin_amdgcn_mfma_f32_16x16x32_f16(Alo, Bhi, zeroC, 0, 0, 0);
        f32x4 Drb = __builtin_amdgcn_mfma_f32_16x16x32_f16(Ahi, Blo, zeroC, 0, 0, 0);

        // prefetches issue AFTER the critical Bhi/Blo+MFMA burst
        __builtin_amdgcn_sched_barrier(0);
        f32x4 xg_nxt = *reinterpret_cast<const f32x4*>(&xg_perm[vc * XRS + xoff]);
        int vn = x[xb + ((s + 2) & (SEQ - 1))];

        float zi = __builtin_fmaf(RSCI, Dra[0] + Drb[0], D[0]);
        float zf = __builtin_fmaf(RSCI, Dra[1] + Drb[1], D[1]);
        float zg = __builtin_fmaf(RSCI, Dra[2] + Drb[2], D[2]);
        float zo = __builtin_fmaf(RSCI, Dra[3] + Drb[3], D[3]);

        float si = sig_exp2(zi);                         // sigma(i)
        float sf = sig_exp2(zf);                         // sigma(f)
        float ug = sig_exp2(zg);                         // sigma(2g)
        float so = sig_exp2(zo);                         // sigma(o)
        float t1 = __builtin_fmaf(-4.0f * LOG2E, ug, 2.0f * LOG2E);  // -2l2e*tanh(g)
        ccs = __builtin_fmaf(sf, ccs, si * t1);          // scaled cell
        float tc = __builtin_fmaf(2.0f, sig_exp2(ccs), -1.0f);       // tanh(c)
        h = so * tc;

        _Float16 hf = (_Float16)h;
        hhi_buf[nb][col][wslot] = hf;
        hlo_buf[nb][col][wslot] = (_Float16)((h - (float)hf) * RSC);

        // relaxed barrier: order LDS only; token prefetch stays in flight
        asm volatile("s_waitcnt lgkmcnt(0)" ::: "memory");
        __builtin_amdgcn_s_barrier();

        xg_cur = xg_nxt;
        vc = vn;
    }

    // ---- final FC (1 unit) + sigmoid: cross-wave reduce over the 32 units ----
    red[col * 33 + 4 * w + q] = h * W_fc[4 * w + q];
    __syncthreads();
    if (w == 0) {
        const float* rr = &red[col * 33];
        float p = 0.f;
#pragma unroll
        for (int u = 0; u < 8; ++u) p += rr[8 * q + u];
        p += __shfl_xor(p, 16);
        p += __shfl_xor(p, 32);
        if (lane < 16) {
            out[blockIdx.x * 16 + col] = sig_exp2(-LOG2E * (p + b_fc[0]));
        }
    }
}

extern "C" void kernel_launch(void* const* d_in, const int* in_sizes, int n_in,
                              void* d_out, int out_size, void* d_ws, size_t ws_size,
                              hipStream_t stream) {
    const int*   x    = (const int*)d_in[0];
    const float* emb  = (const float*)d_in[1];
    const float* W_ih = (const float*)d_in[2];
    const float* W_hh = (const float*)d_in[3];
    const float* b_ih = (const float*)d_in[4];
    const float* b_hh = (const float*)d_in[5];
    const float* W_fc = (const float*)d_in[6];
    const float* b_fc = (const float*)d_in[7];
    float* out = (float*)d_out;

    dim3 grid(BATCH / 16);   // 256 blocks: one 16-elem group per block (1/CU)
    dim3 block(512);         // 8 waves, one mfma row-chunk each
    lstm_seq_classifier<<<grid, block, 0, stream>>>(x, emb, W_ih, W_hh,
                                                    b_ih, b_hh, W_fc, b_fc, out);
}

// Round 17
// 147.243 us; speedup vs baseline: 1.5761x; 1.1105x over previous
//
#include <hip/hip_runtime.h>

#define VOCAB 53
#define EDIM  16
#define H     32
#define SEQ   512
#define BATCH 4096
#define LOG2E 1.4426950408889634f
#define XRS   132   // xg row stride in f32 words (%4==0 for b128 alignment)
#define HS    72    // h-buffer per-col stride in f16
#define RSC   2048.0f      // weight-residual scale (2^11): lo stays f16-normal
#define RSCI  (1.0f/2048.0f)

typedef _Float16 f16x8 __attribute__((ext_vector_type(8)));
typedef float f32x4 __attribute__((ext_vector_type(4)));

__device__ __forceinline__ float exp2_hw(float x) {
    float r; asm("v_exp_f32 %0, %1" : "=v"(r) : "v"(x)); return r;
}
// rcp(1 + 2^xs): sigmoid when xs = -log2e * z (scales pre-folded into tables)
__device__ __forceinline__ float sig_exp2(float xs) {
    return __builtin_amdgcn_rcpf(1.0f + exp2_hw(xs));
}

// permuted row rp = 16*m + 4*s + g  <->  original W row g*32 + (4m+s)
// (mfma chunk m gives lane (q,c) the 4 gates i,f,g,o of unit 4m+q in D[0..3])
__device__ __forceinline__ void decode_row(int rp, int& orig, float& scale) {
    int m = rp >> 4, rem = rp & 15, s = rem >> 2, g = rem & 3;
    orig = g * 32 + 4 * m + s;
    scale = (g == 2) ? (-2.0f * LOG2E) : (-LOG2E);   // g doubled: tanh(g)=2*sig(2g)-1
}

// 256 blocks x 512 threads (8 waves) — R8 structure minus the h-residual
// plane. Each block owns 16 batch elements; each wave one 16-row MFMA chunk.
// h exchanged f16-only via double-buffered padded LDS plane (one b128 read +
// one b16 write per lane-step); WEIGHT residual kept (Alo, x2048 f16) so the
// systematic weight-quantization error stays compensated: 2 independent MFMAs,
// z = D + Dra/2048. h-quantization error (~1e-4/step, random, contractive
// recurrence) is well under the 1e-2 threshold. c kept scaled by -2log2e.
__global__ __launch_bounds__(512, 1)
void lstm_seq_classifier(const int* __restrict__ x,
                         const float* __restrict__ emb,
                         const float* __restrict__ W_ih,
                         const float* __restrict__ W_hh,
                         const float* __restrict__ b_ih,
                         const float* __restrict__ b_hh,
                         const float* __restrict__ W_fc,
                         const float* __restrict__ b_fc,
                         float* __restrict__ out) {
    __shared__ float xg_perm[VOCAB * XRS];                  // 27,984 B (f32 exact)
    __shared__ _Float16 whi[128 * 32];                      // 8,192 B
    __shared__ _Float16 wlo[128 * 32];                      // 8,192 B (x2048 residual)
    __shared__ __align__(16) _Float16 hhi_buf[2][16][HS];   // 4,608 B
    __shared__ float red[16 * 33];                          // 2,112 B

    const int tid  = threadIdx.x;
    const int lane = tid & 63;
    const int w    = tid >> 6;      // wave index = mfma row-chunk m
    const int col  = lane & 15;     // batch column
    const int q    = lane >> 4;

    // ---- vocab -> permuted, scaled gate-preactivation table (f32 exact) ----
    for (int idx = tid; idx < VOCAB * 128; idx += 512) {
        int v = idx >> 7, rp = idx & 127;
        int orig; float scale; decode_row(rp, orig, scale);
        float acc = b_ih[orig] + b_hh[orig];
        const float* ev = emb + v * EDIM;
        const float* wr = W_ih + orig * EDIM;
#pragma unroll
        for (int e = 0; e < EDIM; ++e) acc += ev[e] * wr[e];
        xg_perm[v * XRS + rp] = scale * acc;
    }
    // ---- permuted scaled W_hh as f16 hi + scaled f16 residual ----
    for (int idx = tid; idx < 128 * 32; idx += 512) {
        int rp = idx >> 5, k = idx & 31;
        int orig; float scale; decode_row(rp, orig, scale);
        float wv = scale * W_hh[orig * H + k];
        _Float16 hi = (_Float16)wv;
        whi[idx] = hi;
        wlo[idx] = (_Float16)((wv - (float)hi) * RSC);
    }
    for (int idx = tid; idx < 2 * 16 * HS; idx += 512)
        (&hhi_buf[0][0][0])[idx] = (_Float16)0.f;
    __syncthreads();

    // A fragments: chunk-row = col, k-slot j = unit 8q+j (identity k-order)
    const f16x8 Ahi = *reinterpret_cast<const f16x8*>(&whi[(16 * w + col) * 32 + 8 * q]);
    const f16x8 Alo = *reinterpret_cast<const f16x8*>(&wlo[(16 * w + col) * 32 + 8 * q]);

    const long xb = (long)(blockIdx.x * 16 + col) * SEQ;
    const int xoff = 16 * w + 4 * q;
    int vc = x[xb + 1];
    f32x4 xg_cur = *reinterpret_cast<const f32x4*>(&xg_perm[x[xb] * XRS + xoff]);

    float ccs = 0.0f, h = 0.0f;   // ccs = -2log2e * c
    const f32x4 zeroC = {0.f, 0.f, 0.f, 0.f};

    for (int s = 0; s < SEQ; ++s) {
        int vn = x[xb + ((s + 2) & (SEQ - 1))];                      // prefetch s+2
        f32x4 xg_nxt = *reinterpret_cast<const f32x4*>(
            &xg_perm[vc * XRS + xoff]);                              // prefetch s+1
        const int rb = s & 1, nb = rb ^ 1;
        f16x8 Bhi = *reinterpret_cast<const f16x8*>(&hhi_buf[rb][col][8 * q]);

        // two INDEPENDENT MFMAs (1-deep chain), then combine
        f32x4 D   = __builtin_amdgcn_mfma_f32_16x16x32_f16(Ahi, Bhi, xg_cur, 0, 0, 0);
        f32x4 Dra = __builtin_amdgcn_mfma_f32_16x16x32_f16(Alo, Bhi, zeroC, 0, 0, 0);

        float zi = __builtin_fmaf(RSCI, Dra[0], D[0]);
        float zf = __builtin_fmaf(RSCI, Dra[1], D[1]);
        float zg = __builtin_fmaf(RSCI, Dra[2], D[2]);
        float zo = __builtin_fmaf(RSCI, Dra[3], D[3]);

        float si = sig_exp2(zi);                         // sigma(i)
        float sf = sig_exp2(zf);                         // sigma(f)
        float ug = sig_exp2(zg);                         // sigma(2g)
        float so = sig_exp2(zo);                         // sigma(o)
        float t1 = __builtin_fmaf(-4.0f * LOG2E, ug, 2.0f * LOG2E);  // -2l2e*tanh(g)
        ccs = __builtin_fmaf(sf, ccs, si * t1);          // scaled cell
        float tc = __builtin_fmaf(2.0f, sig_exp2(ccs), -1.0f);       // tanh(c)
        h = so * tc;

        hhi_buf[nb][col][4 * w + q] = (_Float16)h;
        __syncthreads();
        xg_cur = xg_nxt;
        vc = vn;
    }

    // ---- final FC (1 unit) + sigmoid: cross-wave reduce over the 32 units ----
    red[col * 33 + 4 * w + q] = h * W_fc[4 * w + q];
    __syncthreads();
    if (w == 0) {
        const float* rr = &red[col * 33];
        float p = 0.f;
#pragma unroll
        for (int u = 0; u < 8; ++u) p += rr[8 * q + u];
        p += __shfl_xor(p, 16);
        p += __shfl_xor(p, 32);
        if (lane < 16) {
            out[blockIdx.x * 16 + col] = sig_exp2(-LOG2E * (p + b_fc[0]));
        }
    }
}

extern "C" void kernel_launch(void* const* d_in, const int* in_sizes, int n_in,
                              void* d_out, int out_size, void* d_ws, size_t ws_size,
                              hipStream_t stream) {
    const int*   x    = (const int*)d_in[0];
    const float* emb  = (const float*)d_in[1];
    const float* W_ih = (const float*)d_in[2];
    const float* W_hh = (const float*)d_in[3];
    const float* b_ih = (const float*)d_in[4];
    const float* b_hh = (const float*)d_in[5];
    const float* W_fc = (const float*)d_in[6];
    const float* b_fc = (const float*)d_in[7];
    float* out = (float*)d_out;

    dim3 grid(BATCH / 16);   // 256 blocks: one 16-elem group per block (1/CU)
    dim3 block(512);         // 8 waves, one mfma row-chunk each
    lstm_seq_classifier<<<grid, block, 0, stream>>>(x, emb, W_ih, W_hh,
                                                    b_ih, b_hh, W_fc, b_fc, out);
}